// Round 1
// baseline (275.824 us; speedup 1.0000x reference)
//
#include <hip/hip_runtime.h>
#include <math.h>

// ---------------- problem constants ----------------
#define BATCH   16
#define T_LEN   262144
#define NB      16          // biquad stages
#define L       64          // samples per chunk
#define GRP     64          // chunks per group (== wave width)
#define NG      64          // groups per batch  (T_LEN / (L*GRP))
#define NCHUNK  4096        // chunks per batch  (T_LEN / L)

#define DPI 3.14159265358979323846264338327950288

// ---------------- ws layout (in floats) ----------------
// coefs : [16][96]          (80 biquad coefs + in_gain + out_gain)
// AL    : [16][32][32]      A^64   (f32)
// AG    : [16][32][32]      A^4096 (f32)
// Qend  : [16][64][32]      zero-init group-final states
// Sarr  : [16][64][32]      group start states
// P     : [16][4096][32]    zero-init chunk-final states
#define OFF_COEF  0
#define OFF_AL    1536
#define OFF_AG    17920
#define OFF_QEND  34304
#define OFF_SARR  67072
#define OFF_P     102400
// total = 102400 + 16*4096*32 = 2,199,552 floats ≈ 8.4 MB

// ---------------- stage coefficient math (f64) ----------------
__device__ inline void stage_coefs(int i, double fn, double gn, double qn,
                                   double& B0, double& B1, double& B2,
                                   double& A1, double& A2) {
    const double FS = 96000.0;
    double Q    = exp(log(0.5) + qn * (log(16.0) - log(0.5)));
    double gain = -24.0 + gn * 48.0;
    double lo, hi;
    if (i == 0)            { lo = 20.0;   hi = 500.0;   }
    else if (i == 15)      { lo = 5000.0; hi = 20000.0; }
    else if (i == 1 || i == 14) { lo = 50.0; hi = 16000.0; }
    else                   { lo = 100.0;  hi = 15000.0; }
    double fc    = exp(log(lo) + fn * (log(hi) - log(lo)));
    double w0    = 2.0 * DPI * fc / FS;
    double alpha = sin(w0) / (2.0 * Q);
    double c     = cos(w0);
    double b0, b1, b2, a0, a1, a2;
    if (i == 0) {                 // highpass
        b0 = (1.0 + c) * 0.5; b1 = -(1.0 + c); b2 = (1.0 + c) * 0.5;
        a0 = 1.0 + alpha; a1 = -2.0 * c; a2 = 1.0 - alpha;
    } else if (i == 15) {         // lowpass
        b0 = (1.0 - c) * 0.5; b1 = 1.0 - c; b2 = (1.0 - c) * 0.5;
        a0 = 1.0 + alpha; a1 = -2.0 * c; a2 = 1.0 - alpha;
    } else if (i == 1) {          // lowshelf
        double A = pow(10.0, gain / 40.0), sA = sqrt(A);
        b0 = A * ((A + 1.0) - (A - 1.0) * c + 2.0 * sA * alpha);
        b1 = 2.0 * A * ((A - 1.0) - (A + 1.0) * c);
        b2 = A * ((A + 1.0) - (A - 1.0) * c - 2.0 * sA * alpha);
        a0 = (A + 1.0) + (A - 1.0) * c + 2.0 * sA * alpha;
        a1 = -2.0 * ((A - 1.0) + (A + 1.0) * c);
        a2 = (A + 1.0) + (A - 1.0) * c - 2.0 * sA * alpha;
    } else if (i == 14) {         // highshelf
        double A = pow(10.0, gain / 40.0), sA = sqrt(A);
        b0 = A * ((A + 1.0) + (A - 1.0) * c + 2.0 * sA * alpha);
        b1 = -2.0 * A * ((A - 1.0) + (A + 1.0) * c);
        b2 = A * ((A + 1.0) + (A - 1.0) * c - 2.0 * sA * alpha);
        a0 = (A + 1.0) - (A - 1.0) * c + 2.0 * sA * alpha;
        a1 = 2.0 * ((A - 1.0) - (A + 1.0) * c);
        a2 = (A + 1.0) - (A - 1.0) * c - 2.0 * sA * alpha;
    } else {                      // peak
        double A = pow(10.0, gain / 40.0);
        b0 = 1.0 + alpha * A; b1 = -2.0 * c; b2 = 1.0 - alpha * A;
        a0 = 1.0 + alpha / A; a1 = -2.0 * c; a2 = 1.0 - alpha / A;
    }
    B0 = b0 / a0; B1 = b1 / a0; B2 = b2 / a0; A1 = a1 / a0; A2 = a2 / a0;
}

// ---------------- K0: coefs + A^64 + A^4096 per batch ----------------
__global__ __launch_bounds__(256) void k0_setup(const float* __restrict__ params,
                                                float* __restrict__ coefs,
                                                float* __restrict__ AL,
                                                float* __restrict__ AG) {
    int b = blockIdx.x;
    int t = threadIdx.x;
    __shared__ double cf[NB][5];
    __shared__ double M1[32 * 32];
    __shared__ double M2[32 * 32];

    if (t < NB) {
        double B0, B1, B2, A1, A2;
        stage_coefs(t, (double)params[b * 50 + t * 3 + 0],
                       (double)params[b * 50 + t * 3 + 1],
                       (double)params[b * 50 + t * 3 + 2], B0, B1, B2, A1, A2);
        // round to the f32 values the passes will use, keep A consistent
        float f0 = (float)B0, f1 = (float)B1, f2 = (float)B2, f3 = (float)A1, f4 = (float)A2;
        cf[t][0] = (double)f0; cf[t][1] = (double)f1; cf[t][2] = (double)f2;
        cf[t][3] = (double)f3; cf[t][4] = (double)f4;
        float* cp = coefs + b * 96 + t * 5;
        cp[0] = f0; cp[1] = f1; cp[2] = f2; cp[3] = f3; cp[4] = f4;
    }
    if (t == NB) {
        double indb = -60.0 + (double)params[b * 50 + 48] * 60.0;
        coefs[b * 96 + 80] = (float)pow(10.0, indb / 20.0);
    }
    if (t == NB + 1) {
        double outdb = -60.0 + (double)params[b * 50 + 49] * 60.0;
        coefs[b * 96 + 81] = (float)pow(10.0, outdb / 20.0);
    }
    __syncthreads();

    // build A: column t = one cascade step (u=0) applied to unit state e_t
    if (t < 32) {
        double s1[NB], s2[NB];
#pragma unroll
        for (int i = 0; i < NB; i++) {
            s1[i] = (t == 2 * i) ? 1.0 : 0.0;
            s2[i] = (t == 2 * i + 1) ? 1.0 : 0.0;
        }
        double u = 0.0;
#pragma unroll
        for (int i = 0; i < NB; i++) {
            double y  = cf[i][0] * u + s1[i];
            double n1 = cf[i][1] * u - cf[i][3] * y + s2[i];
            double n2 = cf[i][2] * u - cf[i][4] * y;
            s1[i] = n1; s2[i] = n2; u = y;
        }
#pragma unroll
        for (int i = 0; i < NB; i++) {
            M1[(2 * i) * 32 + t]     = s1[i];
            M1[(2 * i + 1) * 32 + t] = s2[i];
        }
    }
    __syncthreads();

    // 12 repeated squarings: A -> A^64 (after 6) -> A^4096 (after 12)
    double* src = M1;
    double* dst = M2;
    for (int sq = 0; sq < 12; sq++) {
#pragma unroll
        for (int e = 0; e < 4; e++) {
            int idx = t * 4 + e;
            int r = idx >> 5, c = idx & 31;
            double acc = 0.0;
            for (int k = 0; k < 32; k++) acc += src[r * 32 + k] * src[k * 32 + c];
            dst[idx] = acc;
        }
        __syncthreads();
        { double* tmp = src; src = dst; dst = tmp; }
        if (sq == 5) {
#pragma unroll
            for (int e = 0; e < 4; e++) { int idx = t * 4 + e; AL[b * 1024 + idx] = (float)src[idx]; }
        }
        if (sq == 11) {
#pragma unroll
            for (int e = 0; e < 4; e++) { int idx = t * 4 + e; AG[b * 1024 + idx] = (float)src[idx]; }
        }
        __syncthreads();
    }
}

// ---------------- K1: zero-init chunk states + group-final states ----------------
__global__ __launch_bounds__(64) void k1_pass1(const float* __restrict__ audio,
                                               const float* __restrict__ coefs,
                                               const float* __restrict__ AL,
                                               float* __restrict__ P,
                                               float* __restrict__ Qend) {
    int blk   = blockIdx.x;          // 0..1023
    int batch = blk >> 6;
    int grp   = blk & 63;
    int lane  = threadIdx.x;
    int chunk = grp * GRP + lane;

    const float* cf = coefs + batch * 96;
    float c0[NB], c1[NB], c2[NB], c3[NB], c4[NB];
#pragma unroll
    for (int i = 0; i < NB; i++) {
        c0[i] = cf[i * 5 + 0]; c1[i] = cf[i * 5 + 1]; c2[i] = cf[i * 5 + 2];
        c3[i] = cf[i * 5 + 3]; c4[i] = cf[i * 5 + 4];
    }
    float ing = cf[80];

    float s1[NB], s2[NB];
#pragma unroll
    for (int i = 0; i < NB; i++) { s1[i] = 0.f; s2[i] = 0.f; }

    const float4* xp = (const float4*)(audio + (size_t)batch * T_LEN + (size_t)chunk * L);
    for (int tt = 0; tt < L / 4; tt++) {
        float4 xv = xp[tt];
        float xs[4] = {xv.x, xv.y, xv.z, xv.w};
#pragma unroll
        for (int j = 0; j < 4; j++) {
            float u = ing * xs[j];
#pragma unroll
            for (int i = 0; i < NB; i++) {
                float y  = fmaf(c0[i], u, s1[i]);
                float n1 = fmaf(c1[i], u, s2[i]); n1 = fmaf(-c3[i], y, n1);
                float n2 = c2[i] * u;             n2 = fmaf(-c4[i], y, n2);
                s1[i] = n1; s2[i] = n2; u = y;
            }
        }
    }

    // write chunk-final state, also stage into LDS for the group prefix
    __shared__ float plds[GRP][33];
    float* pp = P + ((size_t)(batch * NCHUNK + chunk)) * 32;
#pragma unroll
    for (int i = 0; i < NB; i++) {
        float2 v; v.x = s1[i]; v.y = s2[i];
        *(float2*)(pp + 2 * i) = v;
        plds[lane][2 * i]     = s1[i];
        plds[lane][2 * i + 1] = s2[i];
    }
    __syncthreads();

    // in-wave sequential group prefix: q <- A^64 q + p(k), q0 = 0
    if (lane < 32) {
        const float* alr = AL + batch * 1024 + lane * 32;
        float arow[32];
#pragma unroll
        for (int c = 0; c < 32; c++) arow[c] = alr[c];
        float q = 0.f;
        for (int k = 0; k < GRP; k++) {
            float acc = plds[k][lane];
#pragma unroll
            for (int c = 0; c < 32; c++) acc = fmaf(arow[c], __shfl(q, c, 64), acc);
            q = acc;
        }
        Qend[(batch * NG + grp) * 32 + lane] = q;
    }
}

// ---------------- K2: group-level sequential combine per batch ----------------
__global__ __launch_bounds__(64) void k2_combine(const float* __restrict__ AG,
                                                 const float* __restrict__ Qend,
                                                 float* __restrict__ Sarr) {
    int batch = blockIdx.x;
    int lane  = threadIdx.x;
    if (lane >= 32) return;
    const float* agr = AG + batch * 1024 + lane * 32;
    float arow[32];
#pragma unroll
    for (int c = 0; c < 32; c++) arow[c] = agr[c];
    float S = 0.f;
    for (int g = 0; g < NG; g++) {
        Sarr[(batch * NG + g) * 32 + lane] = S;   // state at start of group g
        float acc = Qend[(batch * NG + g) * 32 + lane];
#pragma unroll
        for (int c = 0; c < 32; c++) acc = fmaf(arow[c], __shfl(S, c, 64), acc);
        S = acc;
    }
}

// ---------------- K3: corrected-init re-run, write output ----------------
__global__ __launch_bounds__(64) void k3_pass2(const float* __restrict__ audio,
                                               const float* __restrict__ coefs,
                                               const float* __restrict__ AL,
                                               const float* __restrict__ P,
                                               const float* __restrict__ Sarr,
                                               float* __restrict__ out) {
    int blk   = blockIdx.x;
    int batch = blk >> 6;
    int grp   = blk & 63;
    int lane  = threadIdx.x;

    __shared__ float plds[GRP][33];
    __shared__ float slds[GRP][33];

    const float4* pp4 = (const float4*)(P + ((size_t)(batch * NCHUNK + grp * GRP + lane)) * 32);
#pragma unroll
    for (int r4 = 0; r4 < 8; r4++) {
        float4 v = pp4[r4];
        plds[lane][4 * r4 + 0] = v.x;
        plds[lane][4 * r4 + 1] = v.y;
        plds[lane][4 * r4 + 2] = v.z;
        plds[lane][4 * r4 + 3] = v.w;
    }
    __syncthreads();

    // group prefix seeded with the true group start state; record s_start per chunk
    if (lane < 32) {
        const float* alr = AL + batch * 1024 + lane * 32;
        float arow[32];
#pragma unroll
        for (int c = 0; c < 32; c++) arow[c] = alr[c];
        float q = Sarr[(batch * NG + grp) * 32 + lane];
        for (int k = 0; k < GRP; k++) {
            slds[k][lane] = q;                    // s_start of chunk (grp*64+k)
            float acc = plds[k][lane];
#pragma unroll
            for (int c = 0; c < 32; c++) acc = fmaf(arow[c], __shfl(q, c, 64), acc);
            q = acc;
        }
    }
    __syncthreads();

    const float* cf = coefs + batch * 96;
    float c0[NB], c1[NB], c2[NB], c3[NB], c4[NB];
#pragma unroll
    for (int i = 0; i < NB; i++) {
        c0[i] = cf[i * 5 + 0]; c1[i] = cf[i * 5 + 1]; c2[i] = cf[i * 5 + 2];
        c3[i] = cf[i * 5 + 3]; c4[i] = cf[i * 5 + 4];
    }
    float ing  = cf[80];
    float outg = cf[81];

    float s1[NB], s2[NB];
#pragma unroll
    for (int i = 0; i < NB; i++) {
        s1[i] = slds[lane][2 * i];
        s2[i] = slds[lane][2 * i + 1];
    }

    int chunk = grp * GRP + lane;
    const float4* xp = (const float4*)(audio + (size_t)batch * T_LEN + (size_t)chunk * L);
    float4* yp = (float4*)(out + (size_t)batch * T_LEN + (size_t)chunk * L);
    for (int tt = 0; tt < L / 4; tt++) {
        float4 xv = xp[tt];
        float xs[4] = {xv.x, xv.y, xv.z, xv.w};
        float ys[4];
#pragma unroll
        for (int j = 0; j < 4; j++) {
            float u = ing * xs[j];
#pragma unroll
            for (int i = 0; i < NB; i++) {
                float y  = fmaf(c0[i], u, s1[i]);
                float n1 = fmaf(c1[i], u, s2[i]); n1 = fmaf(-c3[i], y, n1);
                float n2 = c2[i] * u;             n2 = fmaf(-c4[i], y, n2);
                s1[i] = n1; s2[i] = n2; u = y;
            }
            ys[j] = outg * u;
        }
        float4 yv; yv.x = ys[0]; yv.y = ys[1]; yv.z = ys[2]; yv.w = ys[3];
        yp[tt] = yv;
    }
}

// ---------------- launcher ----------------
extern "C" void kernel_launch(void* const* d_in, const int* in_sizes, int n_in,
                              void* d_out, int out_size, void* d_ws, size_t ws_size,
                              hipStream_t stream) {
    const float* audio  = (const float*)d_in[0];
    const float* params = (const float*)d_in[1];
    float* out = (float*)d_out;
    float* ws  = (float*)d_ws;

    float* coefs = ws + OFF_COEF;
    float* AL    = ws + OFF_AL;
    float* AG    = ws + OFF_AG;
    float* Qend  = ws + OFF_QEND;
    float* Sarr  = ws + OFF_SARR;
    float* P     = ws + OFF_P;

    k0_setup<<<BATCH, 256, 0, stream>>>(params, coefs, AL, AG);
    k1_pass1<<<BATCH * NG, 64, 0, stream>>>(audio, coefs, AL, P, Qend);
    k2_combine<<<BATCH, 64, 0, stream>>>(AG, Qend, Sarr);
    k3_pass2<<<BATCH * NG, 64, 0, stream>>>(audio, coefs, AL, P, Sarr, out);
}

// Round 2
// 199.930 us; speedup vs baseline: 1.3796x; 1.3796x over previous
//
#include <hip/hip_runtime.h>
#include <math.h>

// ---------------- problem constants ----------------
#define BATCH   16
#define T_LEN   262144
#define NB      16          // biquad stages
#define L       64          // samples per chunk
#define GRP     64          // chunks per group (== wave width)
#define NG      64          // groups per batch  (T_LEN / (L*GRP))
#define NCHUNK  4096        // chunks per batch  (T_LEN / L)

#define DPI 3.14159265358979323846264338327950288

// ---------------- ws layout (in floats) ----------------
#define OFF_COEF  0
#define OFF_AL    1536
#define OFF_AG    17920
#define OFF_QEND  34304
#define OFF_SARR  67072
#define OFF_P     102400
// total = 102400 + 16*4096*32 = 2,199,552 floats ~= 8.4 MB

// ---------------- stage coefficient math (f64) ----------------
__device__ inline void stage_coefs(int i, double fn, double gn, double qn,
                                   double& B0, double& B1, double& B2,
                                   double& A1, double& A2) {
    const double FS = 96000.0;
    double Q    = exp(log(0.5) + qn * (log(16.0) - log(0.5)));
    double gain = -24.0 + gn * 48.0;
    double lo, hi;
    if (i == 0)            { lo = 20.0;   hi = 500.0;   }
    else if (i == 15)      { lo = 5000.0; hi = 20000.0; }
    else if (i == 1 || i == 14) { lo = 50.0; hi = 16000.0; }
    else                   { lo = 100.0;  hi = 15000.0; }
    double fc    = exp(log(lo) + fn * (log(hi) - log(lo)));
    double w0    = 2.0 * DPI * fc / FS;
    double alpha = sin(w0) / (2.0 * Q);
    double c     = cos(w0);
    double b0, b1, b2, a0, a1, a2;
    if (i == 0) {                 // highpass
        b0 = (1.0 + c) * 0.5; b1 = -(1.0 + c); b2 = (1.0 + c) * 0.5;
        a0 = 1.0 + alpha; a1 = -2.0 * c; a2 = 1.0 - alpha;
    } else if (i == 15) {         // lowpass
        b0 = (1.0 - c) * 0.5; b1 = 1.0 - c; b2 = (1.0 - c) * 0.5;
        a0 = 1.0 + alpha; a1 = -2.0 * c; a2 = 1.0 - alpha;
    } else if (i == 1) {          // lowshelf
        double A = pow(10.0, gain / 40.0), sA = sqrt(A);
        b0 = A * ((A + 1.0) - (A - 1.0) * c + 2.0 * sA * alpha);
        b1 = 2.0 * A * ((A - 1.0) - (A + 1.0) * c);
        b2 = A * ((A + 1.0) - (A - 1.0) * c - 2.0 * sA * alpha);
        a0 = (A + 1.0) + (A - 1.0) * c + 2.0 * sA * alpha;
        a1 = -2.0 * ((A - 1.0) + (A + 1.0) * c);
        a2 = (A + 1.0) + (A - 1.0) * c - 2.0 * sA * alpha;
    } else if (i == 14) {         // highshelf
        double A = pow(10.0, gain / 40.0), sA = sqrt(A);
        b0 = A * ((A + 1.0) + (A - 1.0) * c + 2.0 * sA * alpha);
        b1 = -2.0 * A * ((A - 1.0) + (A + 1.0) * c);
        b2 = A * ((A + 1.0) + (A - 1.0) * c - 2.0 * sA * alpha);
        a0 = (A + 1.0) - (A - 1.0) * c + 2.0 * sA * alpha;
        a1 = 2.0 * ((A - 1.0) - (A + 1.0) * c);
        a2 = (A + 1.0) - (A - 1.0) * c - 2.0 * sA * alpha;
    } else {                      // peak
        double A = pow(10.0, gain / 40.0);
        b0 = 1.0 + alpha * A; b1 = -2.0 * c; b2 = 1.0 - alpha * A;
        a0 = 1.0 + alpha / A; a1 = -2.0 * c; a2 = 1.0 - alpha / A;
    }
    B0 = b0 / a0; B1 = b1 / a0; B2 = b2 / a0; A1 = a1 / a0; A2 = a2 / a0;
}

// ---------------- K0: coefs + A^64 + A^4096 per batch ----------------
__global__ __launch_bounds__(256) void k0_setup(const float* __restrict__ params,
                                                float* __restrict__ coefs,
                                                float* __restrict__ AL,
                                                float* __restrict__ AG) {
    int b = blockIdx.x;
    int t = threadIdx.x;
    __shared__ double cf[NB][5];
    __shared__ double M1[32 * 32];
    __shared__ double M2[32 * 32];

    if (t < NB) {
        double B0, B1, B2, A1, A2;
        stage_coefs(t, (double)params[b * 50 + t * 3 + 0],
                       (double)params[b * 50 + t * 3 + 1],
                       (double)params[b * 50 + t * 3 + 2], B0, B1, B2, A1, A2);
        float f0 = (float)B0, f1 = (float)B1, f2 = (float)B2, f3 = (float)A1, f4 = (float)A2;
        cf[t][0] = (double)f0; cf[t][1] = (double)f1; cf[t][2] = (double)f2;
        cf[t][3] = (double)f3; cf[t][4] = (double)f4;
        float* cp = coefs + b * 96 + t * 5;
        cp[0] = f0; cp[1] = f1; cp[2] = f2; cp[3] = f3; cp[4] = f4;
    }
    if (t == NB) {
        double indb = -60.0 + (double)params[b * 50 + 48] * 60.0;
        coefs[b * 96 + 80] = (float)pow(10.0, indb / 20.0);
    }
    if (t == NB + 1) {
        double outdb = -60.0 + (double)params[b * 50 + 49] * 60.0;
        coefs[b * 96 + 81] = (float)pow(10.0, outdb / 20.0);
    }
    __syncthreads();

    // build A: column t = one cascade step (u=0) applied to unit state e_t
    if (t < 32) {
        double s1[NB], s2[NB];
#pragma unroll
        for (int i = 0; i < NB; i++) {
            s1[i] = (t == 2 * i) ? 1.0 : 0.0;
            s2[i] = (t == 2 * i + 1) ? 1.0 : 0.0;
        }
        double u = 0.0;
#pragma unroll
        for (int i = 0; i < NB; i++) {
            double y  = cf[i][0] * u + s1[i];
            double n1 = cf[i][1] * u - cf[i][3] * y + s2[i];
            double n2 = cf[i][2] * u - cf[i][4] * y;
            s1[i] = n1; s2[i] = n2; u = y;
        }
#pragma unroll
        for (int i = 0; i < NB; i++) {
            M1[(2 * i) * 32 + t]     = s1[i];
            M1[(2 * i + 1) * 32 + t] = s2[i];
        }
    }
    __syncthreads();

    // 12 repeated squarings: A -> A^64 (after 6) -> A^4096 (after 12)
    double* src = M1;
    double* dst = M2;
    for (int sq = 0; sq < 12; sq++) {
#pragma unroll
        for (int e = 0; e < 4; e++) {
            int idx = t * 4 + e;
            int r = idx >> 5, c = idx & 31;
            double acc = 0.0;
            for (int k = 0; k < 32; k++) acc += src[r * 32 + k] * src[k * 32 + c];
            dst[idx] = acc;
        }
        __syncthreads();
        { double* tmp = src; src = dst; dst = tmp; }
        if (sq == 5) {
#pragma unroll
            for (int e = 0; e < 4; e++) { int idx = t * 4 + e; AL[b * 1024 + idx] = (float)src[idx]; }
        }
        if (sq == 11) {
#pragma unroll
            for (int e = 0; e < 4; e++) { int idx = t * 4 + e; AG[b * 1024 + idx] = (float)src[idx]; }
        }
        __syncthreads();
    }
}

// Half-split matvec prefix step:
//   lane = (row = lane&31, half = lane>>5); each lane owns 16 of the 32
//   row coefficients (register-resident), does 16 bpermute+FMA, then one
//   shfl_xor(32) merges the halves so BOTH halves hold the new S[row].
//   Per-step latency ~150-200 cyc vs ~3000 in the round-0 codegen
//   (VGPR=32 forced per-iteration global reloads of the matrix row).

// ---------------- K1: zero-init chunk states + group-final states ----------------
__global__ __launch_bounds__(64, 1) void k1_pass1(const float* __restrict__ audio,
                                                  const float* __restrict__ coefs,
                                                  const float* __restrict__ AL,
                                                  float* __restrict__ P,
                                                  float* __restrict__ Qend) {
    int blk   = blockIdx.x;          // 0..1023
    int batch = blk >> 6;
    int grp   = blk & 63;
    int lane  = threadIdx.x;
    int chunk = grp * GRP + lane;

    const float* cf = coefs + batch * 96;
    float c0[NB], c1[NB], c2[NB], c3[NB], c4[NB];
#pragma unroll
    for (int i = 0; i < NB; i++) {
        c0[i] = cf[i * 5 + 0]; c1[i] = cf[i * 5 + 1]; c2[i] = cf[i * 5 + 2];
        c3[i] = cf[i * 5 + 3]; c4[i] = cf[i * 5 + 4];
    }
    float ing = cf[80];

    float s1[NB], s2[NB];
#pragma unroll
    for (int i = 0; i < NB; i++) { s1[i] = 0.f; s2[i] = 0.f; }

    const float4* xp = (const float4*)(audio + (size_t)batch * T_LEN + (size_t)chunk * L);
    float4 xv = xp[0];
    for (int tt = 0; tt < L / 4; tt++) {
        float4 xn;
        if (tt < L / 4 - 1) xn = xp[tt + 1];
        float xs[4] = {xv.x, xv.y, xv.z, xv.w};
#pragma unroll
        for (int j = 0; j < 4; j++) {
            float u = ing * xs[j];
#pragma unroll
            for (int i = 0; i < NB; i++) {
                float y  = fmaf(c0[i], u, s1[i]);
                float n1 = fmaf(c1[i], u, s2[i]); n1 = fmaf(-c3[i], y, n1);
                float n2 = c2[i] * u;             n2 = fmaf(-c4[i], y, n2);
                s1[i] = n1; s2[i] = n2; u = y;
            }
        }
        xv = xn;
    }

    // write chunk-final state, also stage into LDS for the group prefix
    __shared__ float plds[GRP][33];
    float* pp = P + ((size_t)(batch * NCHUNK + chunk)) * 32;
#pragma unroll
    for (int i = 0; i < NB; i++) {
        float2 v; v.x = s1[i]; v.y = s2[i];
        *(float2*)(pp + 2 * i) = v;
        plds[lane][2 * i]     = s1[i];
        plds[lane][2 * i + 1] = s2[i];
    }
    __syncthreads();

    // in-wave sequential group prefix: q <- A^64 q + p(k), q0 = 0 (half-split)
    int row  = lane & 31;
    int half = lane >> 5;
    const float* alr = AL + batch * 1024 + row * 32 + half * 16;
    float ar[16];
#pragma unroll
    for (int j = 0; j < 16; j++) ar[j] = alr[j];
    float q = 0.f;
    for (int k = 0; k < GRP; k++) {
        float acc = (half == 0) ? plds[k][row] : 0.f;
#pragma unroll
        for (int j = 0; j < 16; j++)
            acc = fmaf(ar[j], __shfl(q, half * 16 + j, 64), acc);
        acc += __shfl_xor(acc, 32, 64);
        q = acc;
    }
    if (lane < 32) Qend[(batch * NG + grp) * 32 + row] = q;
}

// ---------------- K2: group-level sequential combine per batch ----------------
__global__ __launch_bounds__(64, 1) void k2_combine(const float* __restrict__ AG,
                                                    const float* __restrict__ Qend,
                                                    float* __restrict__ Sarr) {
    int batch = blockIdx.x;
    int lane  = threadIdx.x;
    int row   = lane & 31;
    int half  = lane >> 5;

    __shared__ float qe[NG][32];
    __shared__ float ss[NG][32];

    // cooperative coalesced load of Qend[batch] (8 KB) into LDS
    const float4* qsrc = (const float4*)(Qend + (size_t)batch * NG * 32);
    float4* qdst = (float4*)&qe[0][0];
    for (int i = lane; i < NG * 32 / 4; i += 64) qdst[i] = qsrc[i];

    const float* agr = AG + batch * 1024 + row * 32 + half * 16;
    float ar[16];
#pragma unroll
    for (int j = 0; j < 16; j++) ar[j] = agr[j];
    __syncthreads();

    float S = 0.f;
    for (int g = 0; g < NG; g++) {
        if (half == 0) ss[g][row] = S;        // state at start of group g
        float acc = (half == 0) ? qe[g][row] : 0.f;
#pragma unroll
        for (int j = 0; j < 16; j++)
            acc = fmaf(ar[j], __shfl(S, half * 16 + j, 64), acc);
        acc += __shfl_xor(acc, 32, 64);
        S = acc;
    }
    __syncthreads();

    // coalesced dump of start states
    const float4* s4 = (const float4*)&ss[0][0];
    float4* sd = (float4*)(Sarr + (size_t)batch * NG * 32);
    for (int i = lane; i < NG * 32 / 4; i += 64) sd[i] = s4[i];
}

// ---------------- K3: corrected-init re-run, write output ----------------
__global__ __launch_bounds__(64, 1) void k3_pass2(const float* __restrict__ audio,
                                                  const float* __restrict__ coefs,
                                                  const float* __restrict__ AL,
                                                  const float* __restrict__ P,
                                                  const float* __restrict__ Sarr,
                                                  float* __restrict__ out) {
    int blk   = blockIdx.x;
    int batch = blk >> 6;
    int grp   = blk & 63;
    int lane  = threadIdx.x;

    __shared__ float plds[GRP][33];
    __shared__ float slds[GRP][33];

    const float4* pp4 = (const float4*)(P + ((size_t)(batch * NCHUNK + grp * GRP + lane)) * 32);
#pragma unroll
    for (int r4 = 0; r4 < 8; r4++) {
        float4 v = pp4[r4];
        plds[lane][4 * r4 + 0] = v.x;
        plds[lane][4 * r4 + 1] = v.y;
        plds[lane][4 * r4 + 2] = v.z;
        plds[lane][4 * r4 + 3] = v.w;
    }
    __syncthreads();

    // group prefix seeded with the true group start state (half-split);
    // record s_start per chunk into slds.
    {
        int row  = lane & 31;
        int half = lane >> 5;
        const float* alr = AL + batch * 1024 + row * 32 + half * 16;
        float ar[16];
#pragma unroll
        for (int j = 0; j < 16; j++) ar[j] = alr[j];
        float q = Sarr[(batch * NG + grp) * 32 + row];   // replicated in both halves
        for (int k = 0; k < GRP; k++) {
            if (half == 0) slds[k][row] = q;             // s_start of chunk (grp*64+k)
            float acc = (half == 0) ? plds[k][row] : 0.f;
#pragma unroll
            for (int j = 0; j < 16; j++)
                acc = fmaf(ar[j], __shfl(q, half * 16 + j, 64), acc);
            acc += __shfl_xor(acc, 32, 64);
            q = acc;
        }
    }
    __syncthreads();

    const float* cf = coefs + batch * 96;
    float c0[NB], c1[NB], c2[NB], c3[NB], c4[NB];
#pragma unroll
    for (int i = 0; i < NB; i++) {
        c0[i] = cf[i * 5 + 0]; c1[i] = cf[i * 5 + 1]; c2[i] = cf[i * 5 + 2];
        c3[i] = cf[i * 5 + 3]; c4[i] = cf[i * 5 + 4];
    }
    float ing  = cf[80];
    float outg = cf[81];

    float s1[NB], s2[NB];
#pragma unroll
    for (int i = 0; i < NB; i++) {
        s1[i] = slds[lane][2 * i];
        s2[i] = slds[lane][2 * i + 1];
    }

    int chunk = grp * GRP + lane;
    const float4* xp = (const float4*)(audio + (size_t)batch * T_LEN + (size_t)chunk * L);
    float4* yp = (float4*)(out + (size_t)batch * T_LEN + (size_t)chunk * L);
    float4 xv = xp[0];
    for (int tt = 0; tt < L / 4; tt++) {
        float4 xn;
        if (tt < L / 4 - 1) xn = xp[tt + 1];
        float xs[4] = {xv.x, xv.y, xv.z, xv.w};
        float ys[4];
#pragma unroll
        for (int j = 0; j < 4; j++) {
            float u = ing * xs[j];
#pragma unroll
            for (int i = 0; i < NB; i++) {
                float y  = fmaf(c0[i], u, s1[i]);
                float n1 = fmaf(c1[i], u, s2[i]); n1 = fmaf(-c3[i], y, n1);
                float n2 = c2[i] * u;             n2 = fmaf(-c4[i], y, n2);
                s1[i] = n1; s2[i] = n2; u = y;
            }
            ys[j] = outg * u;
        }
        float4 yv; yv.x = ys[0]; yv.y = ys[1]; yv.z = ys[2]; yv.w = ys[3];
        yp[tt] = yv;
        xv = xn;
    }
}

// ---------------- launcher ----------------
extern "C" void kernel_launch(void* const* d_in, const int* in_sizes, int n_in,
                              void* d_out, int out_size, void* d_ws, size_t ws_size,
                              hipStream_t stream) {
    const float* audio  = (const float*)d_in[0];
    const float* params = (const float*)d_in[1];
    float* out = (float*)d_out;
    float* ws  = (float*)d_ws;

    float* coefs = ws + OFF_COEF;
    float* AL    = ws + OFF_AL;
    float* AG    = ws + OFF_AG;
    float* Qend  = ws + OFF_QEND;
    float* Sarr  = ws + OFF_SARR;
    float* P     = ws + OFF_P;

    k0_setup<<<BATCH, 256, 0, stream>>>(params, coefs, AL, AG);
    k1_pass1<<<BATCH * NG, 64, 0, stream>>>(audio, coefs, AL, P, Qend);
    k2_combine<<<BATCH, 64, 0, stream>>>(AG, Qend, Sarr);
    k3_pass2<<<BATCH * NG, 64, 0, stream>>>(audio, coefs, AL, P, Sarr, out);
}

// Round 3
// 161.157 us; speedup vs baseline: 1.7115x; 1.2406x over previous
//
#include <hip/hip_runtime.h>
#include <math.h>

// ---------------- problem constants ----------------
#define BATCH   16
#define T_LEN   262144
#define NB      16          // biquad stages
#define L       64          // samples per chunk
#define GRP     64          // chunks per group (== wave width)
#define NG      64          // groups per batch  (T_LEN / (L*GRP))
#define NCHUNK  4096        // chunks per batch  (T_LEN / L)

#define DPI 3.14159265358979323846264338327950288

// ---------------- ws layout (in floats) ----------------
#define OFF_COEF  0
#define OFF_AL    1536
#define OFF_AG    17920
#define OFF_QEND  34304
#define OFF_SARR  67072
#define OFF_P     102400
// total = 102400 + 16*4096*32 = 2,199,552 floats ~= 8.4 MB

// ---------------- stage coefficient math (f64) ----------------
__device__ inline void stage_coefs(int i, double fn, double gn, double qn,
                                   double& B0, double& B1, double& B2,
                                   double& A1, double& A2) {
    const double FS = 96000.0;
    double Q    = exp(log(0.5) + qn * (log(16.0) - log(0.5)));
    double gain = -24.0 + gn * 48.0;
    double lo, hi;
    if (i == 0)            { lo = 20.0;   hi = 500.0;   }
    else if (i == 15)      { lo = 5000.0; hi = 20000.0; }
    else if (i == 1 || i == 14) { lo = 50.0; hi = 16000.0; }
    else                   { lo = 100.0;  hi = 15000.0; }
    double fc    = exp(log(lo) + fn * (log(hi) - log(lo)));
    double w0    = 2.0 * DPI * fc / FS;
    double alpha = sin(w0) / (2.0 * Q);
    double c     = cos(w0);
    double b0, b1, b2, a0, a1, a2;
    if (i == 0) {                 // highpass
        b0 = (1.0 + c) * 0.5; b1 = -(1.0 + c); b2 = (1.0 + c) * 0.5;
        a0 = 1.0 + alpha; a1 = -2.0 * c; a2 = 1.0 - alpha;
    } else if (i == 15) {         // lowpass
        b0 = (1.0 - c) * 0.5; b1 = 1.0 - c; b2 = (1.0 - c) * 0.5;
        a0 = 1.0 + alpha; a1 = -2.0 * c; a2 = 1.0 - alpha;
    } else if (i == 1) {          // lowshelf
        double A = pow(10.0, gain / 40.0), sA = sqrt(A);
        b0 = A * ((A + 1.0) - (A - 1.0) * c + 2.0 * sA * alpha);
        b1 = 2.0 * A * ((A - 1.0) - (A + 1.0) * c);
        b2 = A * ((A + 1.0) - (A - 1.0) * c - 2.0 * sA * alpha);
        a0 = (A + 1.0) + (A - 1.0) * c + 2.0 * sA * alpha;
        a1 = -2.0 * ((A - 1.0) + (A + 1.0) * c);
        a2 = (A + 1.0) + (A - 1.0) * c - 2.0 * sA * alpha;
    } else if (i == 14) {         // highshelf
        double A = pow(10.0, gain / 40.0), sA = sqrt(A);
        b0 = A * ((A + 1.0) + (A - 1.0) * c + 2.0 * sA * alpha);
        b1 = -2.0 * A * ((A - 1.0) + (A + 1.0) * c);
        b2 = A * ((A + 1.0) + (A - 1.0) * c - 2.0 * sA * alpha);
        a0 = (A + 1.0) - (A - 1.0) * c + 2.0 * sA * alpha;
        a1 = 2.0 * ((A - 1.0) - (A + 1.0) * c);
        a2 = (A + 1.0) - (A - 1.0) * c - 2.0 * sA * alpha;
    } else {                      // peak
        double A = pow(10.0, gain / 40.0);
        b0 = 1.0 + alpha * A; b1 = -2.0 * c; b2 = 1.0 - alpha * A;
        a0 = 1.0 + alpha / A; a1 = -2.0 * c; a2 = 1.0 - alpha / A;
    }
    B0 = b0 / a0; B1 = b1 / a0; B2 = b2 / a0; A1 = a1 / a0; A2 = a2 / a0;
}

// ---------------- K0: coefs + A^64 + A^4096 per batch ----------------
// Squaring mapping: thread t owns column c = t&31, rows r0, r0+8, r0+16, r0+24
// (r0 = t>>5's row block via idx = e*256+t). Consecutive lanes -> consecutive
// columns: the per-k column read is 32 consecutive doubles (2-way bank alias,
// free per m136); row reads are wave-broadcasts. Round-2's idx=t*4+e mapping
// put 64 lanes on 4 banks (16-way conflict, 1.02M conflict cycles, 52 us).
__global__ __launch_bounds__(256) void k0_setup(const float* __restrict__ params,
                                                float* __restrict__ coefs,
                                                float* __restrict__ AL,
                                                float* __restrict__ AG) {
    int b = blockIdx.x;
    int t = threadIdx.x;
    __shared__ double cf[NB][5];
    __shared__ double M1[32 * 32];
    __shared__ double M2[32 * 32];

    if (t < NB) {
        double B0, B1, B2, A1, A2;
        stage_coefs(t, (double)params[b * 50 + t * 3 + 0],
                       (double)params[b * 50 + t * 3 + 1],
                       (double)params[b * 50 + t * 3 + 2], B0, B1, B2, A1, A2);
        float f0 = (float)B0, f1 = (float)B1, f2 = (float)B2, f3 = (float)A1, f4 = (float)A2;
        cf[t][0] = (double)f0; cf[t][1] = (double)f1; cf[t][2] = (double)f2;
        cf[t][3] = (double)f3; cf[t][4] = (double)f4;
        float* cp = coefs + b * 96 + t * 5;
        cp[0] = f0; cp[1] = f1; cp[2] = f2; cp[3] = f3; cp[4] = f4;
    }
    if (t == NB) {
        double indb = -60.0 + (double)params[b * 50 + 48] * 60.0;
        coefs[b * 96 + 80] = (float)pow(10.0, indb / 20.0);
    }
    if (t == NB + 1) {
        double outdb = -60.0 + (double)params[b * 50 + 49] * 60.0;
        coefs[b * 96 + 81] = (float)pow(10.0, outdb / 20.0);
    }
    __syncthreads();

    // build A: column t = one cascade step (u=0) applied to unit state e_t
    if (t < 32) {
        double s1[NB], s2[NB];
#pragma unroll
        for (int i = 0; i < NB; i++) {
            s1[i] = (t == 2 * i) ? 1.0 : 0.0;
            s2[i] = (t == 2 * i + 1) ? 1.0 : 0.0;
        }
        double u = 0.0;
#pragma unroll
        for (int i = 0; i < NB; i++) {
            double y  = cf[i][0] * u + s1[i];
            double n1 = cf[i][1] * u - cf[i][3] * y + s2[i];
            double n2 = cf[i][2] * u - cf[i][4] * y;
            s1[i] = n1; s2[i] = n2; u = y;
        }
#pragma unroll
        for (int i = 0; i < NB; i++) {
            M1[(2 * i) * 32 + t]     = s1[i];
            M1[(2 * i + 1) * 32 + t] = s2[i];
        }
    }
    __syncthreads();

    // 12 repeated squarings: A -> A^64 (after 6) -> A^4096 (after 12)
    int c  = t & 31;
    int r0 = t >> 5;            // rows r0, r0+8, r0+16, r0+24
    double* src = M1;
    double* dst = M2;
    for (int sq = 0; sq < 12; sq++) {
        double acc[4] = {0.0, 0.0, 0.0, 0.0};
        for (int k = 0; k < 32; k++) {
            double bv = src[k * 32 + c];
#pragma unroll
            for (int e = 0; e < 4; e++)
                acc[e] += src[(e * 8 + r0) * 32 + k] * bv;
        }
#pragma unroll
        for (int e = 0; e < 4; e++) dst[(e * 8 + r0) * 32 + c] = acc[e];
        __syncthreads();
        { double* tmp = src; src = dst; dst = tmp; }
        if (sq == 5) {
#pragma unroll
            for (int e = 0; e < 4; e++) {
                int idx = (e * 8 + r0) * 32 + c;
                AL[b * 1024 + idx] = (float)src[idx];
            }
        }
        if (sq == 11) {
#pragma unroll
            for (int e = 0; e < 4; e++) {
                int idx = (e * 8 + r0) * 32 + c;
                AG[b * 1024 + idx] = (float)src[idx];
            }
        }
        __syncthreads();
    }
}

// Half-split matvec prefix step:
//   lane = (row = lane&31, half = lane>>5); each lane owns 16 of the 32
//   row coefficients (register-resident), does 16 bpermute+FMA, then one
//   shfl_xor(32) merges the halves so BOTH halves hold the new S[row].

// ---------------- K1: zero-init chunk states + group-final states ----------------
__global__ __launch_bounds__(64, 1) void k1_pass1(const float* __restrict__ audio,
                                                  const float* __restrict__ coefs,
                                                  const float* __restrict__ AL,
                                                  float* __restrict__ P,
                                                  float* __restrict__ Qend) {
    int blk   = blockIdx.x;          // 0..1023
    int batch = blk >> 6;
    int grp   = blk & 63;
    int lane  = threadIdx.x;
    int chunk = grp * GRP + lane;

    // issue ALL chunk loads up front (1 wave/SIMD: no TLP, so buy ILP —
    // 16 loads in flight instead of a 1-deep prefetch)
    const float4* xp = (const float4*)(audio + (size_t)batch * T_LEN + (size_t)chunk * L);
    float4 xbuf[16];
#pragma unroll
    for (int tt = 0; tt < 16; tt++) xbuf[tt] = xp[tt];

    const float* cf = coefs + batch * 96;
    float c0[NB], c1[NB], c2[NB], c3[NB], c4[NB];
#pragma unroll
    for (int i = 0; i < NB; i++) {
        c0[i] = cf[i * 5 + 0]; c1[i] = cf[i * 5 + 1]; c2[i] = cf[i * 5 + 2];
        c3[i] = cf[i * 5 + 3]; c4[i] = cf[i * 5 + 4];
    }
    float ing = cf[80];

    float s1[NB], s2[NB];
#pragma unroll
    for (int i = 0; i < NB; i++) { s1[i] = 0.f; s2[i] = 0.f; }

#pragma unroll
    for (int tt = 0; tt < 16; tt++) {
        float xs[4] = {xbuf[tt].x, xbuf[tt].y, xbuf[tt].z, xbuf[tt].w};
#pragma unroll
        for (int j = 0; j < 4; j++) {
            float u = ing * xs[j];
#pragma unroll
            for (int i = 0; i < NB; i++) {
                float y  = fmaf(c0[i], u, s1[i]);
                float n1 = fmaf(c1[i], u, s2[i]); n1 = fmaf(-c3[i], y, n1);
                float n2 = c2[i] * u;             n2 = fmaf(-c4[i], y, n2);
                s1[i] = n1; s2[i] = n2; u = y;
            }
        }
    }

    // write chunk-final state, also stage into LDS for the group prefix
    __shared__ float plds[GRP][33];
    float* pp = P + ((size_t)(batch * NCHUNK + chunk)) * 32;
#pragma unroll
    for (int i = 0; i < NB; i++) {
        float2 v; v.x = s1[i]; v.y = s2[i];
        *(float2*)(pp + 2 * i) = v;
        plds[lane][2 * i]     = s1[i];
        plds[lane][2 * i + 1] = s2[i];
    }
    __syncthreads();

    // in-wave sequential group prefix: q <- A^64 q + p(k), q0 = 0 (half-split)
    int row  = lane & 31;
    int half = lane >> 5;
    const float* alr = AL + batch * 1024 + row * 32 + half * 16;
    float ar[16];
#pragma unroll
    for (int j = 0; j < 16; j++) ar[j] = alr[j];
    float q = 0.f;
    for (int k = 0; k < GRP; k++) {
        float acc = (half == 0) ? plds[k][row] : 0.f;
#pragma unroll
        for (int j = 0; j < 16; j++)
            acc = fmaf(ar[j], __shfl(q, half * 16 + j, 64), acc);
        acc += __shfl_xor(acc, 32, 64);
        q = acc;
    }
    if (lane < 32) Qend[(batch * NG + grp) * 32 + row] = q;
}

// ---------------- K2: group-level sequential combine per batch ----------------
__global__ __launch_bounds__(64, 1) void k2_combine(const float* __restrict__ AG,
                                                    const float* __restrict__ Qend,
                                                    float* __restrict__ Sarr) {
    int batch = blockIdx.x;
    int lane  = threadIdx.x;
    int row   = lane & 31;
    int half  = lane >> 5;

    __shared__ float qe[NG][32];
    __shared__ float ss[NG][32];

    // cooperative coalesced load of Qend[batch] (8 KB) into LDS
    const float4* qsrc = (const float4*)(Qend + (size_t)batch * NG * 32);
    float4* qdst = (float4*)&qe[0][0];
    for (int i = lane; i < NG * 32 / 4; i += 64) qdst[i] = qsrc[i];

    const float* agr = AG + batch * 1024 + row * 32 + half * 16;
    float ar[16];
#pragma unroll
    for (int j = 0; j < 16; j++) ar[j] = agr[j];
    __syncthreads();

    float S = 0.f;
    for (int g = 0; g < NG; g++) {
        if (half == 0) ss[g][row] = S;        // state at start of group g
        float acc = (half == 0) ? qe[g][row] : 0.f;
#pragma unroll
        for (int j = 0; j < 16; j++)
            acc = fmaf(ar[j], __shfl(S, half * 16 + j, 64), acc);
        acc += __shfl_xor(acc, 32, 64);
        S = acc;
    }
    __syncthreads();

    // coalesced dump of start states
    const float4* s4 = (const float4*)&ss[0][0];
    float4* sd = (float4*)(Sarr + (size_t)batch * NG * 32);
    for (int i = lane; i < NG * 32 / 4; i += 64) sd[i] = s4[i];
}

// ---------------- K3: corrected-init re-run, write output ----------------
__global__ __launch_bounds__(64, 1) void k3_pass2(const float* __restrict__ audio,
                                                  const float* __restrict__ coefs,
                                                  const float* __restrict__ AL,
                                                  const float* __restrict__ P,
                                                  const float* __restrict__ Sarr,
                                                  float* __restrict__ out) {
    int blk   = blockIdx.x;
    int batch = blk >> 6;
    int grp   = blk & 63;
    int lane  = threadIdx.x;
    int chunk = grp * GRP + lane;

    // start audio loads first (longest latency, used last)
    const float4* xp = (const float4*)(audio + (size_t)batch * T_LEN + (size_t)chunk * L);
    float4 xbuf[16];
#pragma unroll
    for (int tt = 0; tt < 16; tt++) xbuf[tt] = xp[tt];

    __shared__ float plds[GRP][33];
    __shared__ float slds[GRP][33];

    const float4* pp4 = (const float4*)(P + ((size_t)(batch * NCHUNK + chunk)) * 32);
#pragma unroll
    for (int r4 = 0; r4 < 8; r4++) {
        float4 v = pp4[r4];
        plds[lane][4 * r4 + 0] = v.x;
        plds[lane][4 * r4 + 1] = v.y;
        plds[lane][4 * r4 + 2] = v.z;
        plds[lane][4 * r4 + 3] = v.w;
    }
    __syncthreads();

    // group prefix seeded with the true group start state (half-split);
    // record s_start per chunk into slds.
    {
        int row  = lane & 31;
        int half = lane >> 5;
        const float* alr = AL + batch * 1024 + row * 32 + half * 16;
        float ar[16];
#pragma unroll
        for (int j = 0; j < 16; j++) ar[j] = alr[j];
        float q = Sarr[(batch * NG + grp) * 32 + row];   // replicated in both halves
        for (int k = 0; k < GRP; k++) {
            if (half == 0) slds[k][row] = q;             // s_start of chunk (grp*64+k)
            float acc = (half == 0) ? plds[k][row] : 0.f;
#pragma unroll
            for (int j = 0; j < 16; j++)
                acc = fmaf(ar[j], __shfl(q, half * 16 + j, 64), acc);
            acc += __shfl_xor(acc, 32, 64);
            q = acc;
        }
    }
    __syncthreads();

    const float* cf = coefs + batch * 96;
    float c0[NB], c1[NB], c2[NB], c3[NB], c4[NB];
#pragma unroll
    for (int i = 0; i < NB; i++) {
        c0[i] = cf[i * 5 + 0]; c1[i] = cf[i * 5 + 1]; c2[i] = cf[i * 5 + 2];
        c3[i] = cf[i * 5 + 3]; c4[i] = cf[i * 5 + 4];
    }
    float ing  = cf[80];
    float outg = cf[81];

    float s1[NB], s2[NB];
#pragma unroll
    for (int i = 0; i < NB; i++) {
        s1[i] = slds[lane][2 * i];
        s2[i] = slds[lane][2 * i + 1];
    }

    float4* yp = (float4*)(out + (size_t)batch * T_LEN + (size_t)chunk * L);
#pragma unroll
    for (int tt = 0; tt < 16; tt++) {
        float xs[4] = {xbuf[tt].x, xbuf[tt].y, xbuf[tt].z, xbuf[tt].w};
        float ys[4];
#pragma unroll
        for (int j = 0; j < 4; j++) {
            float u = ing * xs[j];
#pragma unroll
            for (int i = 0; i < NB; i++) {
                float y  = fmaf(c0[i], u, s1[i]);
                float n1 = fmaf(c1[i], u, s2[i]); n1 = fmaf(-c3[i], y, n1);
                float n2 = c2[i] * u;             n2 = fmaf(-c4[i], y, n2);
                s1[i] = n1; s2[i] = n2; u = y;
            }
            ys[j] = outg * u;
        }
        float4 yv; yv.x = ys[0]; yv.y = ys[1]; yv.z = ys[2]; yv.w = ys[3];
        yp[tt] = yv;
    }
}

// ---------------- launcher ----------------
extern "C" void kernel_launch(void* const* d_in, const int* in_sizes, int n_in,
                              void* d_out, int out_size, void* d_ws, size_t ws_size,
                              hipStream_t stream) {
    const float* audio  = (const float*)d_in[0];
    const float* params = (const float*)d_in[1];
    float* out = (float*)d_out;
    float* ws  = (float*)d_ws;

    float* coefs = ws + OFF_COEF;
    float* AL    = ws + OFF_AL;
    float* AG    = ws + OFF_AG;
    float* Qend  = ws + OFF_QEND;
    float* Sarr  = ws + OFF_SARR;
    float* P     = ws + OFF_P;

    k0_setup<<<BATCH, 256, 0, stream>>>(params, coefs, AL, AG);
    k1_pass1<<<BATCH * NG, 64, 0, stream>>>(audio, coefs, AL, P, Qend);
    k2_combine<<<BATCH, 64, 0, stream>>>(AG, Qend, Sarr);
    k3_pass2<<<BATCH * NG, 64, 0, stream>>>(audio, coefs, AL, P, Sarr, out);
}